// Round 4
// baseline (227.239 us; speedup 1.0000x reference)
//
#include <hip/hip_runtime.h>
#include <hip/hip_bf16.h>
#include <math.h>

#define T_TOK 2048
#define H_DIM 2048
#define E_EXP 16
#define I_DIM 512
#define TWO_I 1024
#define ROUTED_SCALE 1.5f
#define SWIGLU_LIMIT 7.0f

#define BM 64
#define KC 64
#define MAX_TILES 80

typedef __attribute__((ext_vector_type(8))) short bf16x8;
typedef __attribute__((ext_vector_type(4))) float f32x4;
typedef unsigned short u16;

__device__ inline u16 f2bf(float f) {
    return __builtin_bit_cast(u16, __float2bfloat16(f));
}
__device__ inline bf16x8 pack8(float4 a, float4 b) {
    bf16x8 v;
    v[0] = (short)f2bf(a.x); v[1] = (short)f2bf(a.y);
    v[2] = (short)f2bf(a.z); v[3] = (short)f2bf(a.w);
    v[4] = (short)f2bf(b.x); v[5] = (short)f2bf(b.y);
    v[6] = (short)f2bf(b.z); v[7] = (short)f2bf(b.w);
    return v;
}

// async 16B global->LDS (lane scatters at ldsbase + lane*16)
__device__ inline void gload16(const u16* g, u16* l) {
    __builtin_amdgcn_global_load_lds(
        (const __attribute__((address_space(1))) void*)(g),
        (__attribute__((address_space(3))) void*)(l), 16, 0, 0);
}

// swizzled ushort index for 64-elem bf16 rows: logical (row,k) -> row*64 + (k ^ ((row&7)<<3))
#define SWZ(row, k) ((row) * 64 + ((k) ^ (((row) & 7) << 3)))

// ---------------- weight convert: fp32 -> bf16 ----------------
#define NV13 4194304   // w13 elems/8
#define NVTOT 6291456  // (w13+w2) elems/8
__global__ __launch_bounds__(256) void convert_w(
    const float* __restrict__ w13, const float* __restrict__ w2,
    u16* __restrict__ w13b, u16* __restrict__ w2b)
{
    int stride = gridDim.x * 256;
    for (size_t v = blockIdx.x * 256 + threadIdx.x; v < NVTOT; v += stride) {
        const float* s; u16* d;
        if (v < NV13) { s = w13 + v * 8; d = w13b + v * 8; }
        else          { s = w2 + (v - NV13) * 8; d = w2b + (v - NV13) * 8; }
        float4 a = *(const float4*)s;
        float4 b = *(const float4*)(s + 4);
        *(bf16x8*)d = pack8(a, b);
    }
}

// ---------------- router: one wave per token; also emits hs in bf16 ----------------
__global__ __launch_bounds__(256) void router_kernel(
    const float* __restrict__ hs, const float* __restrict__ gw,
    const float* __restrict__ bias, int* cnt, int* tok_list, float* w_list,
    u16* __restrict__ hs_bf)
{
    int wave = threadIdx.x >> 6;
    int lane = threadIdx.x & 63;
    int t = blockIdx.x * 4 + wave;
    if (t >= T_TOK) return;
    const float* x = hs + (size_t)t * H_DIM;

    float acc[E_EXP];
#pragma unroll
    for (int e = 0; e < E_EXP; ++e) acc[e] = 0.f;

#pragma unroll 2
    for (int c = 0; c < 8; ++c) {
        int col = c * 256 + lane * 4;
        float4 xv = *(const float4*)(x + col);
        ushort4 pv;
        pv.x = f2bf(xv.x); pv.y = f2bf(xv.y); pv.z = f2bf(xv.z); pv.w = f2bf(xv.w);
        *(ushort4*)(hs_bf + (size_t)t * H_DIM + col) = pv;
#pragma unroll
        for (int e = 0; e < E_EXP; ++e) {
            float4 gv = *(const float4*)(gw + (size_t)e * H_DIM + col);
            acc[e] = fmaf(xv.x, gv.x, acc[e]);
            acc[e] = fmaf(xv.y, gv.y, acc[e]);
            acc[e] = fmaf(xv.z, gv.z, acc[e]);
            acc[e] = fmaf(xv.w, gv.w, acc[e]);
        }
    }
#pragma unroll
    for (int e = 0; e < E_EXP; ++e) {
        for (int m = 32; m >= 1; m >>= 1)
            acc[e] += __shfl_xor(acc[e], m, 64);
    }
    if (lane == 0) {
        float sc[E_EXP], bsc[E_EXP];
#pragma unroll
        for (int e = 0; e < E_EXP; ++e) {
            sc[e] = 1.f / (1.f + expf(-acc[e]));
            bsc[e] = sc[e] + bias[e];
        }
        int e0 = 0; float b0 = bsc[0];
#pragma unroll
        for (int e = 1; e < E_EXP; ++e) if (bsc[e] > b0) { b0 = bsc[e]; e0 = e; }
        int e1 = -1; float b1 = -1e30f;
#pragma unroll
        for (int e = 0; e < E_EXP; ++e) {
            if (e == e0) continue;
            if (bsc[e] > b1) { b1 = bsc[e]; e1 = e; }
        }
        float s0 = sc[e0], s1 = sc[e1];
        float inv = ROUTED_SCALE / (s0 + s1);
        int p0 = atomicAdd(&cnt[e0], 1);
        tok_list[e0 * T_TOK + p0] = t;
        w_list[e0 * T_TOK + p0] = s0 * inv;
        int p1 = atomicAdd(&cnt[e1], 1);
        tok_list[e1 * T_TOK + p1] = t;
        w_list[e1 * T_TOK + p1] = s1 * inv;
    }
}

// ---------------- fused: compact assignments + tile descriptors ----------------
__global__ void scatter_build(const int* __restrict__ cnt,
    const int* __restrict__ tok_list, const float* __restrict__ w_list,
    int* A_tok, float* A_w, int* tile_e, int* tile_r0)
{
    int c[E_EXP], offs[E_EXP + 1];
    offs[0] = 0;
#pragma unroll
    for (int e = 0; e < E_EXP; ++e) {
        c[e] = cnt[e];
        offs[e + 1] = offs[e] + ((c[e] + BM - 1) & ~(BM - 1));
    }
    int idx = blockIdx.x * 256 + threadIdx.x;
    int e = idx >> 11;
    int pos = idx & (T_TOK - 1);
    int ce = c[e];
    int pe = (ce + BM - 1) & ~(BM - 1);
    if (pos < ce) {
        A_tok[offs[e] + pos] = tok_list[idx];
        A_w[offs[e] + pos] = w_list[idx];
    } else if (pos < pe) {
        A_tok[offs[e] + pos] = -1;
        A_w[offs[e] + pos] = 0.f;
    }
    if (idx == 0) {
        int nt = 0;
        for (int ee = 0; ee < E_EXP; ++ee) {
            int ntile = (c[ee] + BM - 1) >> 6;
            for (int j = 0; j < ntile; ++j) {
                tile_e[nt] = ee;
                tile_r0[nt] = offs[ee] + j * BM;
                ++nt;
            }
        }
        for (; nt < MAX_TILES; ++nt) tile_e[nt] = -1;
    }
}

// ================= bf16-weight path (async global_load_lds staging) =================

// ---------------- GEMM1 bf16: X @ [G;U]^T -> SwiGLU -> act ----------------
__global__ __launch_bounds__(256, 3) void gemm1_bf(
    const u16* __restrict__ hs_bf, const u16* __restrict__ w13b,
    const int* __restrict__ A_tok, const int* __restrict__ tile_e,
    const int* __restrict__ tile_r0, u16* __restrict__ act)
{
    int b = blockIdx.x;
    int id = (b & 7) * 80 + (b >> 3);
    int tile = id % MAX_TILES;
    int y = id / MAX_TILES;              // 0..7
    int e = tile_e[tile];
    if (e < 0) return;
    int row0 = tile_r0[tile];
    int i0 = y * 64;
    int tid = threadIdx.x;

    __shared__ u16 Xs[2][4096];
    __shared__ u16 Gs[2][4096];
    __shared__ u16 Us[2][4096];

    const int l = tid & 63, w = tid >> 6;
    // staging lane roles: lane covers 8 bf16 at physical (row, kswz=c8); source k = c8 ^ (rlo<<3)
    const int rlo = l >> 3;              // 0..7
    const int c8 = (l & 7) << 3;
    const int ksrc = c8 ^ (rlo << 3);
    const int rowA = w * 16 + rlo;       // issue 0 rows
    const int rowB = rowA + 8;           // issue 1 rows
    int tokA = A_tok[row0 + rowA]; if (tokA < 0) tokA = 0;   // pad rows read token0 (masked later)
    int tokB = A_tok[row0 + rowB]; if (tokB < 0) tokB = 0;
    const u16* sXA = hs_bf + (size_t)tokA * H_DIM + ksrc;
    const u16* sXB = hs_bf + (size_t)tokB * H_DIM + ksrc;
    const u16* sGA = w13b + ((size_t)e * TWO_I + i0 + rowA) * H_DIM + ksrc;
    const u16* sGB = sGA + 8 * H_DIM;
    const u16* sUA = sGA + (size_t)I_DIM * H_DIM;
    const u16* sUB = sUA + 8 * H_DIM;
    const int dA = w * 1024;             // wave-uniform LDS elem offset (16 rows/wave)

#define G1STAGE(bb, t) do { int ko = (t) * KC; \
    gload16(sXA + ko, &Xs[bb][dA]);  gload16(sXB + ko, &Xs[bb][dA + 512]); \
    gload16(sGA + ko, &Gs[bb][dA]);  gload16(sGB + ko, &Gs[bb][dA + 512]); \
    gload16(sUA + ko, &Us[bb][dA]);  gload16(sUB + ko, &Us[bb][dA + 512]); } while (0)

    // MFMA roles: 4 waves as 2x2 over (token32, i32)
    const int wm = w >> 1, wn = w & 1;
    const int lr = l & 15;
    const int lg = l >> 4;
    const int ra0 = wm * 32 + lr, ra1 = ra0 + 16;
    const int rb0 = wn * 32 + lr, rb1 = rb0 + 16;
    int ia0[2], ia1[2], ib0[2], ib1[2];
#pragma unroll
    for (int kh = 0; kh < 2; ++kh) {
        int e2 = kh * 32 + lg * 8;
        ia0[kh] = SWZ(ra0, e2); ia1[kh] = SWZ(ra1, e2);
        ib0[kh] = SWZ(rb0, e2); ib1[kh] = SWZ(rb1, e2);
    }

    const f32x4 Z4 = {0.f, 0.f, 0.f, 0.f};
    f32x4 aG[2][2], aU[2][2];
#pragma unroll
    for (int m = 0; m < 2; ++m)
#pragma unroll
        for (int n = 0; n < 2; ++n) { aG[m][n] = Z4; aU[m][n] = Z4; }

    G1STAGE(0, 0);
    __syncthreads();
    int cur = 0;
    const int NT = H_DIM / KC;           // 32
    for (int t = 0; t < NT; ++t) {
        if (t + 1 < NT) G1STAGE(cur ^ 1, t + 1);
#pragma unroll
        for (int kh = 0; kh < 2; ++kh) {
            bf16x8 a0 = *(const bf16x8*)&Xs[cur][ia0[kh]];
            bf16x8 a1 = *(const bf16x8*)&Xs[cur][ia1[kh]];
            bf16x8 g0 = *(const bf16x8*)&Gs[cur][ib0[kh]];
            bf16x8 g1 = *(const bf16x8*)&Gs[cur][ib1[kh]];
            bf16x8 u0 = *(const bf16x8*)&Us[cur][ib0[kh]];
            bf16x8 u1 = *(const bf16x8*)&Us[cur][ib1[kh]];
            aG[0][0] = __builtin_amdgcn_mfma_f32_16x16x32_bf16(a0, g0, aG[0][0], 0, 0, 0);
            aG[0][1] = __builtin_amdgcn_mfma_f32_16x16x32_bf16(a0, g1, aG[0][1], 0, 0, 0);
            aG[1][0] = __builtin_amdgcn_mfma_f32_16x16x32_bf16(a1, g0, aG[1][0], 0, 0, 0);
            aG[1][1] = __builtin_amdgcn_mfma_f32_16x16x32_bf16(a1, g1, aG[1][1], 0, 0, 0);
            aU[0][0] = __builtin_amdgcn_mfma_f32_16x16x32_bf16(a0, u0, aU[0][0], 0, 0, 0);
            aU[0][1] = __builtin_amdgcn_mfma_f32_16x16x32_bf16(a0, u1, aU[0][1], 0, 0, 0);
            aU[1][0] = __builtin_amdgcn_mfma_f32_16x16x32_bf16(a1, u0, aU[1][0], 0, 0, 0);
            aU[1][1] = __builtin_amdgcn_mfma_f32_16x16x32_bf16(a1, u1, aU[1][1], 0, 0, 0);
        }
        __syncthreads();                 // drains vmcnt(0)+lgkmcnt(0): next buffer ready
        cur ^= 1;
    }
#undef G1STAGE

#pragma unroll
    for (int m = 0; m < 2; ++m)
#pragma unroll
        for (int n = 0; n < 2; ++n) {
            int col = i0 + wn * 32 + n * 16 + lr;
            int rbase = row0 + wm * 32 + m * 16 + lg * 4;
#pragma unroll
            for (int q = 0; q < 4; ++q) {
                float g = fminf(aG[m][n][q], SWIGLU_LIMIT);
                float u = fminf(fmaxf(aU[m][n][q], -SWIGLU_LIMIT), SWIGLU_LIMIT);
                float s = 1.f / (1.f + __expf(-g));
                act[(size_t)(rbase + q) * I_DIM + col] = f2bf(g * s * u);
            }
        }
}

// ---------------- GEMM2 bf16: act @ w2^T * comb -> scatter-add ----------------
__global__ __launch_bounds__(256, 4) void gemm2_bf(
    const u16* __restrict__ act, const u16* __restrict__ w2b,
    const int* __restrict__ A_tok, const float* __restrict__ A_w,
    const int* __restrict__ tile_e, const int* __restrict__ tile_r0,
    float* __restrict__ out)
{
    int b = blockIdx.x;
    int id = (b & 7) * 320 + (b >> 3);
    int tile = id % MAX_TILES;
    int y = id / MAX_TILES;              // 0..31
    int e = tile_e[tile];
    if (e < 0) return;
    int row0 = tile_r0[tile];
    int h0 = y * 64;
    int tid = threadIdx.x;

    __shared__ u16 As[2][4096];
    __shared__ u16 Bs[2][4096];
    __shared__ int toks[BM];
    __shared__ float wts[BM];
    if (tid < BM) { toks[tid] = A_tok[row0 + tid]; wts[tid] = A_w[row0 + tid]; }

    const int l = tid & 63, w = tid >> 6;
    const int rlo = l >> 3;
    const int c8 = (l & 7) << 3;
    const int ksrc = c8 ^ (rlo << 3);
    const int rowA = w * 16 + rlo;
    const int rowB = rowA + 8;
    const u16* sAA = act + (size_t)(row0 + rowA) * I_DIM + ksrc;
    const u16* sAB = act + (size_t)(row0 + rowB) * I_DIM + ksrc;
    const u16* sBA = w2b + ((size_t)e * H_DIM + h0 + rowA) * I_DIM + ksrc;
    const u16* sBB = sBA + 8 * I_DIM;
    const int dA = w * 1024;

#define G2STAGE(bb, t) do { int ko = (t) * KC; \
    gload16(sAA + ko, &As[bb][dA]);  gload16(sAB + ko, &As[bb][dA + 512]); \
    gload16(sBA + ko, &Bs[bb][dA]);  gload16(sBB + ko, &Bs[bb][dA + 512]); } while (0)

    const int wm = w >> 1, wn = w & 1;
    const int lr = l & 15;
    const int lg = l >> 4;
    const int ra0 = wm * 32 + lr, ra1 = ra0 + 16;
    const int rb0 = wn * 32 + lr, rb1 = rb0 + 16;
    int ia0[2], ia1[2], ib0[2], ib1[2];
#pragma unroll
    for (int kh = 0; kh < 2; ++kh) {
        int e2 = kh * 32 + lg * 8;
        ia0[kh] = SWZ(ra0, e2); ia1[kh] = SWZ(ra1, e2);
        ib0[kh] = SWZ(rb0, e2); ib1[kh] = SWZ(rb1, e2);
    }

    const f32x4 Z4 = {0.f, 0.f, 0.f, 0.f};
    f32x4 acc[2][2];
#pragma unroll
    for (int m = 0; m < 2; ++m)
#pragma unroll
        for (int n = 0; n < 2; ++n) acc[m][n] = Z4;

    G2STAGE(0, 0);
    __syncthreads();
    int cur = 0;
    const int NT = I_DIM / KC;           // 8
    for (int t = 0; t < NT; ++t) {
        if (t + 1 < NT) G2STAGE(cur ^ 1, t + 1);
#pragma unroll
        for (int kh = 0; kh < 2; ++kh) {
            bf16x8 a0 = *(const bf16x8*)&As[cur][ia0[kh]];
            bf16x8 a1 = *(const bf16x8*)&As[cur][ia1[kh]];
            bf16x8 b0 = *(const bf16x8*)&Bs[cur][ib0[kh]];
            bf16x8 b1 = *(const bf16x8*)&Bs[cur][ib1[kh]];
            acc[0][0] = __builtin_amdgcn_mfma_f32_16x16x32_bf16(a0, b0, acc[0][0], 0, 0, 0);
            acc[0][1] = __builtin_amdgcn_mfma_f32_16x16x32_bf16(a0, b1, acc[0][1], 0, 0, 0);
            acc[1][0] = __builtin_amdgcn_mfma_f32_16x16x32_bf16(a1, b0, acc[1][0], 0, 0, 0);
            acc[1][1] = __builtin_amdgcn_mfma_f32_16x16x32_bf16(a1, b1, acc[1][1], 0, 0, 0);
        }
        __syncthreads();
        cur ^= 1;
    }
#undef G2STAGE

#pragma unroll
    for (int m = 0; m < 2; ++m)
#pragma unroll
        for (int n = 0; n < 2; ++n) {
            int col = h0 + wn * 32 + n * 16 + lr;
            int sbase = wm * 32 + m * 16 + lg * 4;
#pragma unroll
            for (int q = 0; q < 4; ++q) {
                int slot = sbase + q;
                int tok = toks[slot];
                if (tok >= 0)
                    atomicAdd(&out[(size_t)tok * H_DIM + col], acc[m][n][q] * wts[slot]);
            }
        }
}

// ================= fp32-weight fallback path (round-3 kernels) =================

__global__ __launch_bounds__(256, 3) void gemm1_f32(
    const u16* __restrict__ hs_bf, const float* __restrict__ w13,
    const int* __restrict__ A_tok,
    const int* __restrict__ tile_e, const int* __restrict__ tile_r0,
    u16* __restrict__ act)
{
    int b = blockIdx.x;
    int id = (b & 7) * 80 + (b >> 3);
    int tile = id % MAX_TILES;
    int y = id / MAX_TILES;
    int e = tile_e[tile];
    if (e < 0) return;
    int row0 = tile_r0[tile];
    int i0 = y * 64;
    int tid = threadIdx.x;

    __shared__ u16 Xs[2][4096];
    __shared__ u16 Gs[2][4096];
    __shared__ u16 Us[2][4096];

    const int r  = tid >> 2;
    const int kq = tid & 3;
    const int tok_r = A_tok[row0 + r];
    const bool xok = tok_r >= 0;
    const u16* xsrc = hs_bf + (size_t)(xok ? tok_r : 0) * H_DIM + kq * 16;
    const float* gsrc = w13 + ((size_t)e * TWO_I + i0 + r) * H_DIM + kq * 16;
    const float* usrc = gsrc + (size_t)I_DIM * H_DIM;
    const int wb0 = SWZ(r, kq * 16);
    const int wb1 = SWZ(r, kq * 16 + 8);
    const bf16x8 BZ = {0, 0, 0, 0, 0, 0, 0, 0};

    bf16x8 xv0, xv1;
    float4 gv0, gv1, gv2, gv3, uv0, uv1, uv2, uv3;

#define G1_LOAD(t) do { int k0 = (t) * KC; \
    xv0 = xok ? *(const bf16x8*)(xsrc + k0)     : BZ; \
    xv1 = xok ? *(const bf16x8*)(xsrc + k0 + 8) : BZ; \
    gv0 = *(const float4*)(gsrc + k0);      gv1 = *(const float4*)(gsrc + k0 + 4); \
    gv2 = *(const float4*)(gsrc + k0 + 8);  gv3 = *(const float4*)(gsrc + k0 + 12); \
    uv0 = *(const float4*)(usrc + k0);      uv1 = *(const float4*)(usrc + k0 + 4); \
    uv2 = *(const float4*)(usrc + k0 + 8);  uv3 = *(const float4*)(usrc + k0 + 12); } while (0)
#define G1_WRITE(bb) do { \
    *(bf16x8*)&Xs[bb][wb0] = xv0;             *(bf16x8*)&Xs[bb][wb1] = xv1; \
    *(bf16x8*)&Gs[bb][wb0] = pack8(gv0, gv1); *(bf16x8*)&Gs[bb][wb1] = pack8(gv2, gv3); \
    *(bf16x8*)&Us[bb][wb0] = pack8(uv0, uv1); *(bf16x8*)&Us[bb][wb1] = pack8(uv2, uv3); } while (0)

    const int l  = tid & 63;
    const int w  = tid >> 6;
    const int wm = w >> 1, wn = w & 1;
    const int lr = l & 15;
    const int lg = l >> 4;
    const int ra0 = wm * 32 + lr, ra1 = ra0 + 16;
    const int rb0 = wn * 32 + lr, rb1 = rb0 + 16;
    int ia0[2], ia1[2], ib0[2], ib1[2];
#pragma unroll
    for (int kh = 0; kh < 2; ++kh) {
        int e2 = kh * 32 + lg * 8;
        ia0[kh] = SWZ(ra0, e2); ia1[kh] = SWZ(ra1, e2);
        ib0[kh] = SWZ(rb0, e2); ib1[kh] = SWZ(rb1, e2);
    }

    const f32x4 Z4 = {0.f, 0.f, 0.f, 0.f};
    f32x4 aG[2][2], aU[2][2];
#pragma unroll
    for (int m = 0; m < 2; ++m)
#pragma unroll
        for (int n = 0; n < 2; ++n) { aG[m][n] = Z4; aU[m][n] = Z4; }

    G1_LOAD(0);
    G1_WRITE(0);
    __syncthreads();
    int cur = 0;
    const int NT = H_DIM / KC;
    for (int t = 0; t < NT; ++t) {
        int tn = (t + 1 < NT) ? t + 1 : t;
        G1_LOAD(tn);
#pragma unroll
        for (int kh = 0; kh < 2; ++kh) {
            bf16x8 a0 = *(const bf16x8*)&Xs[cur][ia0[kh]];
            bf16x8 a1 = *(const bf16x8*)&Xs[cur][ia1[kh]];
            bf16x8 g0 = *(const bf16x8*)&Gs[cur][ib0[kh]];
            bf16x8 g1 = *(const bf16x8*)&Gs[cur][ib1[kh]];
            bf16x8 u0 = *(const bf16x8*)&Us[cur][ib0[kh]];
            bf16x8 u1 = *(const bf16x8*)&Us[cur][ib1[kh]];
            aG[0][0] = __builtin_amdgcn_mfma_f32_16x16x32_bf16(a0, g0, aG[0][0], 0, 0, 0);
            aG[0][1] = __builtin_amdgcn_mfma_f32_16x16x32_bf16(a0, g1, aG[0][1], 0, 0, 0);
            aG[1][0] = __builtin_amdgcn_mfma_f32_16x16x32_bf16(a1, g0, aG[1][0], 0, 0, 0);
            aG[1][1] = __builtin_amdgcn_mfma_f32_16x16x32_bf16(a1, g1, aG[1][1], 0, 0, 0);
            aU[0][0] = __builtin_amdgcn_mfma_f32_16x16x32_bf16(a0, u0, aU[0][0], 0, 0, 0);
            aU[0][1] = __builtin_amdgcn_mfma_f32_16x16x32_bf16(a0, u1, aU[0][1], 0, 0, 0);
            aU[1][0] = __builtin_amdgcn_mfma_f32_16x16x32_bf16(a1, u0, aU[1][0], 0, 0, 0);
            aU[1][1] = __builtin_amdgcn_mfma_f32_16x16x32_bf16(a1, u1, aU[1][1], 0, 0, 0);
        }
        G1_WRITE(cur ^ 1);
        __syncthreads();
        cur ^= 1;
    }
#undef G1_LOAD
#undef G1_WRITE

#pragma unroll
    for (int m = 0; m < 2; ++m)
#pragma unroll
        for (int n = 0; n < 2; ++n) {
            int col = i0 + wn * 32 + n * 16 + lr;
            int rbase = row0 + wm * 32 + m * 16 + lg * 4;
#pragma unroll
            for (int q = 0; q < 4; ++q) {
                float g = fminf(aG[m][n][q], SWIGLU_LIMIT);
                float u = fminf(fmaxf(aU[m][n][q], -SWIGLU_LIMIT), SWIGLU_LIMIT);
                float s = 1.f / (1.f + __expf(-g));
                act[(size_t)(rbase + q) * I_DIM + col] = f2bf(g * s * u);
            }
        }
}

__global__ __launch_bounds__(256, 4) void gemm2_f32(
    const u16* __restrict__ act, const float* __restrict__ w2,
    const int* __restrict__ A_tok, const float* __restrict__ A_w,
    const int* __restrict__ tile_e, const int* __restrict__ tile_r0,
    float* __restrict__ out)
{
    int b = blockIdx.x;
    int id = (b & 7) * 320 + (b >> 3);
    int tile = id % MAX_TILES;
    int y = id / MAX_TILES;
    int e = tile_e[tile];
    if (e < 0) return;
    int row0 = tile_r0[tile];
    int h0 = y * 64;
    int tid = threadIdx.x;

    __shared__ u16 As[2][4096];
    __shared__ u16 Bs[2][4096];
    __shared__ int toks[BM];
    __shared__ float wts[BM];
    if (tid < BM) { toks[tid] = A_tok[row0 + tid]; wts[tid] = A_w[row0 + tid]; }

    const int r  = tid >> 2;
    const int kq = tid & 3;
    const u16* asrc = act + (size_t)(row0 + r) * I_DIM + kq * 16;
    const float* bsrc = w2 + ((size_t)e * H_DIM + h0 + r) * I_DIM + kq * 16;
    const int wb0 = SWZ(r, kq * 16);
    const int wb1 = SWZ(r, kq * 16 + 8);

    bf16x8 av0, av1;
    float4 bv0, bv1, bv2, bv3;

#define G2_LOAD(t) do { int k0 = (t) * KC; \
    av0 = *(const bf16x8*)(asrc + k0); av1 = *(const bf16x8*)(asrc + k0 + 8); \
    bv0 = *(const float4*)(bsrc + k0);      bv1 = *(const float4*)(bsrc + k0 + 4); \
    bv2 = *(const float4*)(bsrc + k0 + 8);  bv3 = *(const float4*)(bsrc + k0 + 12); } while (0)
#define G2_WRITE(bb) do { \
    *(bf16x8*)&As[bb][wb0] = av0;             *(bf16x8*)&As[bb][wb1] = av1; \
    *(bf16x8*)&Bs[bb][wb0] = pack8(bv0, bv1); *(bf16x8*)&Bs[bb][wb1] = pack8(bv2, bv3); } while (0)

    const int l  = tid & 63;
    const int w  = tid >> 6;
    const int wm = w >> 1, wn = w & 1;
    const int lr = l & 15;
    const int lg = l >> 4;
    const int ra0 = wm * 32 + lr, ra1 = ra0 + 16;
    const int rb0 = wn * 32 + lr, rb1 = rb0 + 16;
    int ia0[2], ia1[2], ib0[2], ib1[2];
#pragma unroll
    for (int kh = 0; kh < 2; ++kh) {
        int e2 = kh * 32 + lg * 8;
        ia0[kh] = SWZ(ra0, e2); ia1[kh] = SWZ(ra1, e2);
        ib0[kh] = SWZ(rb0, e2); ib1[kh] = SWZ(rb1, e2);
    }

    const f32x4 Z4 = {0.f, 0.f, 0.f, 0.f};
    f32x4 acc[2][2];
#pragma unroll
    for (int m = 0; m < 2; ++m)
#pragma unroll
        for (int n = 0; n < 2; ++n) acc[m][n] = Z4;

    G2_LOAD(0);
    G2_WRITE(0);
    __syncthreads();
    int cur = 0;
    const int NT = I_DIM / KC;
    for (int t = 0; t < NT; ++t) {
        int tn = (t + 1 < NT) ? t + 1 : t;
        G2_LOAD(tn);
#pragma unroll
        for (int kh = 0; kh < 2; ++kh) {
            bf16x8 a0 = *(const bf16x8*)&As[cur][ia0[kh]];
            bf16x8 a1 = *(const bf16x8*)&As[cur][ia1[kh]];
            bf16x8 b0 = *(const bf16x8*)&Bs[cur][ib0[kh]];
            bf16x8 b1 = *(const bf16x8*)&Bs[cur][ib1[kh]];
            acc[0][0] = __builtin_amdgcn_mfma_f32_16x16x32_bf16(a0, b0, acc[0][0], 0, 0, 0);
            acc[0][1] = __builtin_amdgcn_mfma_f32_16x16x32_bf16(a0, b1, acc[0][1], 0, 0, 0);
            acc[1][0] = __builtin_amdgcn_mfma_f32_16x16x32_bf16(a1, b0, acc[1][0], 0, 0, 0);
            acc[1][1] = __builtin_amdgcn_mfma_f32_16x16x32_bf16(a1, b1, acc[1][1], 0, 0, 0);
        }
        G2_WRITE(cur ^ 1);
        __syncthreads();
        cur ^= 1;
    }
#undef G2_LOAD
#undef G2_WRITE

#pragma unroll
    for (int m = 0; m < 2; ++m)
#pragma unroll
        for (int n = 0; n < 2; ++n) {
            int col = h0 + wn * 32 + n * 16 + lr;
            int sbase = wm * 32 + m * 16 + lg * 4;
#pragma unroll
            for (int q = 0; q < 4; ++q) {
                int slot = sbase + q;
                int tok = toks[slot];
                if (tok >= 0)
                    atomicAdd(&out[(size_t)tok * H_DIM + col], acc[m][n][q] * wts[slot]);
            }
        }
}

extern "C" void kernel_launch(void* const* d_in, const int* in_sizes, int n_in,
                              void* d_out, int out_size, void* d_ws, size_t ws_size,
                              hipStream_t stream) {
    const float* hs   = (const float*)d_in[0];
    const float* gw   = (const float*)d_in[1];
    const float* bias = (const float*)d_in[2];
    const float* w13  = (const float*)d_in[3];
    const float* w2   = (const float*)d_in[4];
    float* out = (float*)d_out;

    char* ws = (char*)d_ws;
    int*   cnt      = (int*)(ws + 0);
    int*   tile_e   = (int*)(ws + 64);
    int*   tile_r0  = (int*)(ws + 384);
    int*   tok_list = (int*)(ws + 1024);
    float* w_list   = (float*)(ws + 132096);
    int*   A_tok    = (int*)(ws + 263168);
    float* A_w      = (float*)(ws + 283648);
    u16*   act      = (u16*)(ws + 304128);       // 5 MB
    u16*   hs_bf    = (u16*)(ws + 5547008);      // 8 MB
    u16*   w13b     = (u16*)(ws + 13935616);     // 64 MB
    u16*   w2b      = (u16*)(ws + 81044480);     // 32 MB -> end 114598912
    const size_t NEED_BF = 114598912;
    const bool bf_path = ws_size >= NEED_BF;

    hipMemsetAsync(d_out, 0, (size_t)T_TOK * H_DIM * sizeof(float), stream);
    hipMemsetAsync(cnt, 0, 64, stream);

    if (bf_path)
        convert_w<<<3072, 256, 0, stream>>>(w13, w2, w13b, w2b);

    router_kernel<<<T_TOK / 4, 256, 0, stream>>>(hs, gw, bias, cnt, tok_list, w_list, hs_bf);
    scatter_build<<<(E_EXP * T_TOK) / 256, 256, 0, stream>>>(cnt, tok_list, w_list, A_tok, A_w, tile_e, tile_r0);

    if (bf_path) {
        gemm1_bf<<<MAX_TILES * 8, 256, 0, stream>>>(hs_bf, w13b, A_tok, tile_e, tile_r0, act);
        gemm2_bf<<<MAX_TILES * 32, 256, 0, stream>>>(act, w2b, A_tok, A_w, tile_e, tile_r0, out);
    } else {
        gemm1_f32<<<MAX_TILES * 8, 256, 0, stream>>>(hs_bf, w13, A_tok, tile_e, tile_r0, act);
        gemm2_f32<<<MAX_TILES * 32, 256, 0, stream>>>(act, w2, A_tok, A_w, tile_e, tile_r0, out);
    }
}

// Round 5
// 178.018 us; speedup vs baseline: 1.2765x; 1.2765x over previous
//
#include <hip/hip_runtime.h>
#include <hip/hip_bf16.h>
#include <math.h>

#define T_TOK 2048
#define H_DIM 2048
#define E_EXP 16
#define I_DIM 512
#define TWO_I 1024
#define ROUTED_SCALE 1.5f
#define SWIGLU_LIMIT 7.0f

#define BM 64
#define KC 64
#define MAX_TILES 80

typedef __attribute__((ext_vector_type(8))) short bf16x8;
typedef __attribute__((ext_vector_type(4))) float f32x4;
typedef unsigned short u16;

__device__ inline u16 f2bf(float f) {
    return __builtin_bit_cast(u16, __float2bfloat16(f));
}
__device__ inline ushort4 pack4(float4 a) {
    ushort4 v;
    v.x = f2bf(a.x); v.y = f2bf(a.y); v.z = f2bf(a.z); v.w = f2bf(a.w);
    return v;
}

// async 16B global->LDS (lane scatters at ldsbase + lane*16)
__device__ inline void gload16(const u16* g, u16* l) {
    __builtin_amdgcn_global_load_lds(
        (const __attribute__((address_space(1))) void*)(g),
        (__attribute__((address_space(3))) void*)(l), 16, 0, 0);
}

// swizzled ushort index for 64-elem bf16 rows: logical (row,k) -> row*64 + (k ^ ((row&7)<<3))
#define SWZ(row, k) ((row) * 64 + ((k) ^ (((row) & 7) << 3)))

// ---------------- router: one wave per token; also emits hs in bf16 ----------------
__global__ __launch_bounds__(256) void router_kernel(
    const float* __restrict__ hs, const float* __restrict__ gw,
    const float* __restrict__ bias, int* cnt, int* tok_list, float* w_list,
    u16* __restrict__ hs_bf)
{
    int wave = threadIdx.x >> 6;
    int lane = threadIdx.x & 63;
    int t = blockIdx.x * 4 + wave;
    if (t >= T_TOK) return;
    const float* x = hs + (size_t)t * H_DIM;

    float acc[E_EXP];
#pragma unroll
    for (int e = 0; e < E_EXP; ++e) acc[e] = 0.f;

#pragma unroll 2
    for (int c = 0; c < 8; ++c) {
        int col = c * 256 + lane * 4;
        float4 xv = *(const float4*)(x + col);
        *(ushort4*)(hs_bf + (size_t)t * H_DIM + col) = pack4(xv);
#pragma unroll
        for (int e = 0; e < E_EXP; ++e) {
            float4 gv = *(const float4*)(gw + (size_t)e * H_DIM + col);
            acc[e] = fmaf(xv.x, gv.x, acc[e]);
            acc[e] = fmaf(xv.y, gv.y, acc[e]);
            acc[e] = fmaf(xv.z, gv.z, acc[e]);
            acc[e] = fmaf(xv.w, gv.w, acc[e]);
        }
    }
#pragma unroll
    for (int e = 0; e < E_EXP; ++e) {
        for (int m = 32; m >= 1; m >>= 1)
            acc[e] += __shfl_xor(acc[e], m, 64);
    }
    if (lane == 0) {
        float sc[E_EXP], bsc[E_EXP];
#pragma unroll
        for (int e = 0; e < E_EXP; ++e) {
            sc[e] = 1.f / (1.f + expf(-acc[e]));
            bsc[e] = sc[e] + bias[e];
        }
        int e0 = 0; float b0 = bsc[0];
#pragma unroll
        for (int e = 1; e < E_EXP; ++e) if (bsc[e] > b0) { b0 = bsc[e]; e0 = e; }
        int e1 = -1; float b1 = -1e30f;
#pragma unroll
        for (int e = 0; e < E_EXP; ++e) {
            if (e == e0) continue;
            if (bsc[e] > b1) { b1 = bsc[e]; e1 = e; }
        }
        float s0 = sc[e0], s1 = sc[e1];
        float inv = ROUTED_SCALE / (s0 + s1);
        int p0 = atomicAdd(&cnt[e0], 1);
        tok_list[e0 * T_TOK + p0] = t;
        w_list[e0 * T_TOK + p0] = s0 * inv;
        int p1 = atomicAdd(&cnt[e1], 1);
        tok_list[e1 * T_TOK + p1] = t;
        w_list[e1 * T_TOK + p1] = s1 * inv;
    }
}

// ---------------- fused: compact assignments + tile descriptors ----------------
__global__ void scatter_build(const int* __restrict__ cnt,
    const int* __restrict__ tok_list, const float* __restrict__ w_list,
    int* A_tok, float* A_w, int* tile_e, int* tile_r0)
{
    int c[E_EXP], offs[E_EXP + 1];
    offs[0] = 0;
#pragma unroll
    for (int e = 0; e < E_EXP; ++e) {
        c[e] = cnt[e];
        offs[e + 1] = offs[e] + ((c[e] + BM - 1) & ~(BM - 1));
    }
    int idx = blockIdx.x * 256 + threadIdx.x;
    int e = idx >> 11;
    int pos = idx & (T_TOK - 1);
    int ce = c[e];
    int pe = (ce + BM - 1) & ~(BM - 1);
    if (pos < ce) {
        A_tok[offs[e] + pos] = tok_list[idx];
        A_w[offs[e] + pos] = w_list[idx];
    } else if (pos < pe) {
        A_tok[offs[e] + pos] = -1;
        A_w[offs[e] + pos] = 0.f;
    }
    if (idx == 0) {
        int nt = 0;
        for (int ee = 0; ee < E_EXP; ++ee) {
            int ntile = (c[ee] + BM - 1) >> 6;
            for (int j = 0; j < ntile; ++j) {
                tile_e[nt] = ee;
                tile_r0[nt] = offs[ee] + j * BM;
                ++nt;
            }
        }
        for (; nt < MAX_TILES; ++nt) tile_e[nt] = -1;
    }
}

// ---------------- GEMM1: X(bf16, gload_lds) @ w13(fp32, reg-staged->bf16)^T -> SwiGLU -> act ----------------
__global__ __launch_bounds__(256, 3) void gemm1_act(
    const u16* __restrict__ hs_bf, const float* __restrict__ w13,
    const int* __restrict__ A_tok, const int* __restrict__ tile_e,
    const int* __restrict__ tile_r0, u16* __restrict__ act)
{
    int b = blockIdx.x;
    int id = (b & 7) * 80 + (b >> 3);      // XCD-chunked bijective swizzle (640 = 8*80)
    int tile = id % MAX_TILES;
    int y = id / MAX_TILES;                // 0..7
    int e = tile_e[tile];
    if (e < 0) return;
    int row0 = tile_r0[tile];
    int i0 = y * 64;
    int tid = threadIdx.x;

    __shared__ u16 Xs[2][4096];
    __shared__ u16 Gs[2][4096];
    __shared__ u16 Us[2][4096];

    const int l = tid & 63, w = tid >> 6;

    // ---- X staging via global_load_lds (pre-swizzled source, linear dest) ----
    const int rlo = l >> 3;                // 0..7
    const int c8 = (l & 7) << 3;
    const int ksrc = c8 ^ (rlo << 3);
    const int rowA = w * 16 + rlo;
    const int rowB = rowA + 8;
    int tokA = A_tok[row0 + rowA]; if (tokA < 0) tokA = 0;   // pad rows masked in epilogue via A_w=0
    int tokB = A_tok[row0 + rowB]; if (tokB < 0) tokB = 0;
    const u16* sXA = hs_bf + (size_t)tokA * H_DIM + ksrc;
    const u16* sXB = hs_bf + (size_t)tokB * H_DIM + ksrc;
    const int dA = w * 1024;

#define X_STAGE(bb, t) do { int ko = (t) * KC; \
    gload16(sXA + ko, &Xs[bb][dA]);  gload16(sXB + ko, &Xs[bb][dA + 512]); } while (0)

    // ---- weight staging: dense fp32 loads -> regs -> convert -> swizzled ds_write ----
    // thread: rows srow + j*16 (j=0..3), float4 col sc4 -> lanes 0..15 contiguous 256B
    const int srow = tid >> 4;             // 0..15
    const int sc4  = tid & 15;
    const int kphys = (sc4 * 4) ^ ((srow & 7) << 3);
    const int sbase = srow * 64 + kphys;   // elem offset in LDS tile; +j*1024
    const float* gsrc = w13 + ((size_t)e * TWO_I + i0 + srow) * H_DIM + sc4 * 4;
    const float* usrc = gsrc + (size_t)I_DIM * H_DIM;

    float4 gld[4], uld[4];
#define W_LOAD(t) do { int k0 = (t) * KC; \
    gld[0] = *(const float4*)(gsrc + k0); \
    gld[1] = *(const float4*)(gsrc + k0 + 16 * H_DIM); \
    gld[2] = *(const float4*)(gsrc + k0 + 32 * H_DIM); \
    gld[3] = *(const float4*)(gsrc + k0 + 48 * H_DIM); \
    uld[0] = *(const float4*)(usrc + k0); \
    uld[1] = *(const float4*)(usrc + k0 + 16 * H_DIM); \
    uld[2] = *(const float4*)(usrc + k0 + 32 * H_DIM); \
    uld[3] = *(const float4*)(usrc + k0 + 48 * H_DIM); } while (0)

#define W_WRITE(bb) do { \
    *(ushort4*)&Gs[bb][sbase]        = pack4(gld[0]); \
    *(ushort4*)&Gs[bb][sbase + 1024] = pack4(gld[1]); \
    *(ushort4*)&Gs[bb][sbase + 2048] = pack4(gld[2]); \
    *(ushort4*)&Gs[bb][sbase + 3072] = pack4(gld[3]); \
    *(ushort4*)&Us[bb][sbase]        = pack4(uld[0]); \
    *(ushort4*)&Us[bb][sbase + 1024] = pack4(uld[1]); \
    *(ushort4*)&Us[bb][sbase + 2048] = pack4(uld[2]); \
    *(ushort4*)&Us[bb][sbase + 3072] = pack4(uld[3]); } while (0)

    // ---- MFMA roles: 4 waves as 2x2 over (token32, i32) ----
    const int wm = w >> 1, wn = w & 1;
    const int lr = l & 15;
    const int lg = l >> 4;
    const int ra0 = wm * 32 + lr, ra1 = ra0 + 16;
    const int rb0 = wn * 32 + lr, rb1 = rb0 + 16;
    int ia0[2], ia1[2], ib0[2], ib1[2];
#pragma unroll
    for (int kh = 0; kh < 2; ++kh) {
        int e2 = kh * 32 + lg * 8;
        ia0[kh] = SWZ(ra0, e2); ia1[kh] = SWZ(ra1, e2);
        ib0[kh] = SWZ(rb0, e2); ib1[kh] = SWZ(rb1, e2);
    }

    const f32x4 Z4 = {0.f, 0.f, 0.f, 0.f};
    f32x4 aG[2][2], aU[2][2];
#pragma unroll
    for (int m = 0; m < 2; ++m)
#pragma unroll
        for (int n = 0; n < 2; ++n) { aG[m][n] = Z4; aU[m][n] = Z4; }

    // prologue: fill buffer 0
    W_LOAD(0);
    X_STAGE(0, 0);
    W_WRITE(0);
    __syncthreads();
    int cur = 0;
    const int NT = H_DIM / KC;             // 32
    for (int t = 0; t < NT; ++t) {
        const bool more = (t + 1 < NT);
        if (more) {
            X_STAGE(cur ^ 1, t + 1);
            W_LOAD(t + 1);
            __builtin_amdgcn_sched_barrier(0);   // pin load-issue before MFMA phase
        }
#pragma unroll
        for (int kh = 0; kh < 2; ++kh) {
            bf16x8 a0 = *(const bf16x8*)&Xs[cur][ia0[kh]];
            bf16x8 a1 = *(const bf16x8*)&Xs[cur][ia1[kh]];
            bf16x8 g0 = *(const bf16x8*)&Gs[cur][ib0[kh]];
            bf16x8 g1 = *(const bf16x8*)&Gs[cur][ib1[kh]];
            bf16x8 u0 = *(const bf16x8*)&Us[cur][ib0[kh]];
            bf16x8 u1 = *(const bf16x8*)&Us[cur][ib1[kh]];
            aG[0][0] = __builtin_amdgcn_mfma_f32_16x16x32_bf16(a0, g0, aG[0][0], 0, 0, 0);
            aG[0][1] = __builtin_amdgcn_mfma_f32_16x16x32_bf16(a0, g1, aG[0][1], 0, 0, 0);
            aG[1][0] = __builtin_amdgcn_mfma_f32_16x16x32_bf16(a1, g0, aG[1][0], 0, 0, 0);
            aG[1][1] = __builtin_amdgcn_mfma_f32_16x16x32_bf16(a1, g1, aG[1][1], 0, 0, 0);
            aU[0][0] = __builtin_amdgcn_mfma_f32_16x16x32_bf16(a0, u0, aU[0][0], 0, 0, 0);
            aU[0][1] = __builtin_amdgcn_mfma_f32_16x16x32_bf16(a0, u1, aU[0][1], 0, 0, 0);
            aU[1][0] = __builtin_amdgcn_mfma_f32_16x16x32_bf16(a1, u0, aU[1][0], 0, 0, 0);
            aU[1][1] = __builtin_amdgcn_mfma_f32_16x16x32_bf16(a1, u1, aU[1][1], 0, 0, 0);
        }
        if (more) W_WRITE(cur ^ 1);        // vmcnt wait lands here, after MFMA phase
        __syncthreads();
        cur ^= 1;
    }
#undef X_STAGE
#undef W_LOAD
#undef W_WRITE

#pragma unroll
    for (int m = 0; m < 2; ++m)
#pragma unroll
        for (int n = 0; n < 2; ++n) {
            int col = i0 + wn * 32 + n * 16 + lr;
            int rbase = row0 + wm * 32 + m * 16 + lg * 4;
#pragma unroll
            for (int q = 0; q < 4; ++q) {
                float g = fminf(aG[m][n][q], SWIGLU_LIMIT);
                float u = fminf(fmaxf(aU[m][n][q], -SWIGLU_LIMIT), SWIGLU_LIMIT);
                float s = 1.f / (1.f + __expf(-g));
                act[(size_t)(rbase + q) * I_DIM + col] = f2bf(g * s * u);
            }
        }
}

// ---------------- GEMM2: act(bf16, gload_lds) @ w2(fp32, reg-staged)^T * comb -> scatter-add ----------------
__global__ __launch_bounds__(256, 3) void gemm2_scatter(
    const u16* __restrict__ act, const float* __restrict__ w2,
    const int* __restrict__ A_tok, const float* __restrict__ A_w,
    const int* __restrict__ tile_e, const int* __restrict__ tile_r0,
    float* __restrict__ out)
{
    int b = blockIdx.x;
    int id = (b & 7) * 320 + (b >> 3);     // 2560 = 8*320
    int tile = id % MAX_TILES;
    int y = id / MAX_TILES;                // 0..31
    int e = tile_e[tile];
    if (e < 0) return;
    int row0 = tile_r0[tile];
    int h0 = y * 64;
    int tid = threadIdx.x;

    __shared__ u16 As[2][4096];
    __shared__ u16 Bs[2][4096];
    __shared__ int toks[BM];
    __shared__ float wts[BM];
    if (tid < BM) { toks[tid] = A_tok[row0 + tid]; wts[tid] = A_w[row0 + tid]; }

    const int l = tid & 63, w = tid >> 6;

    const int rlo = l >> 3;
    const int c8 = (l & 7) << 3;
    const int ksrc = c8 ^ (rlo << 3);
    const int rowA = w * 16 + rlo;
    const int rowB = rowA + 8;
    const u16* sAA = act + (size_t)(row0 + rowA) * I_DIM + ksrc;
    const u16* sAB = act + (size_t)(row0 + rowB) * I_DIM + ksrc;
    const int dA = w * 1024;

#define A_STAGE(bb, t) do { int ko = (t) * KC; \
    gload16(sAA + ko, &As[bb][dA]);  gload16(sAB + ko, &As[bb][dA + 512]); } while (0)

    const int srow = tid >> 4;
    const int sc4  = tid & 15;
    const int kphys = (sc4 * 4) ^ ((srow & 7) << 3);
    const int sbase = srow * 64 + kphys;
    const float* bsrc = w2 + ((size_t)e * H_DIM + h0 + srow) * I_DIM + sc4 * 4;

    float4 bld[4];
#define B_LOAD(t) do { int k0 = (t) * KC; \
    bld[0] = *(const float4*)(bsrc + k0); \
    bld[1] = *(const float4*)(bsrc + k0 + 16 * I_DIM); \
    bld[2] = *(const float4*)(bsrc + k0 + 32 * I_DIM); \
    bld[3] = *(const float4*)(bsrc + k0 + 48 * I_DIM); } while (0)

#define B_WRITE(bb) do { \
    *(ushort4*)&Bs[bb][sbase]        = pack4(bld[0]); \
    *(ushort4*)&Bs[bb][sbase + 1024] = pack4(bld[1]); \
    *(ushort4*)&Bs[bb][sbase + 2048] = pack4(bld[2]); \
    *(ushort4*)&Bs[bb][sbase + 3072] = pack4(bld[3]); } while (0)

    const int wm = w >> 1, wn = w & 1;
    const int lr = l & 15;
    const int lg = l >> 4;
    const int ra0 = wm * 32 + lr, ra1 = ra0 + 16;
    const int rb0 = wn * 32 + lr, rb1 = rb0 + 16;
    int ia0[2], ia1[2], ib0[2], ib1[2];
#pragma unroll
    for (int kh = 0; kh < 2; ++kh) {
        int e2 = kh * 32 + lg * 8;
        ia0[kh] = SWZ(ra0, e2); ia1[kh] = SWZ(ra1, e2);
        ib0[kh] = SWZ(rb0, e2); ib1[kh] = SWZ(rb1, e2);
    }

    const f32x4 Z4 = {0.f, 0.f, 0.f, 0.f};
    f32x4 acc[2][2];
#pragma unroll
    for (int m = 0; m < 2; ++m)
#pragma unroll
        for (int n = 0; n < 2; ++n) acc[m][n] = Z4;

    B_LOAD(0);
    A_STAGE(0, 0);
    B_WRITE(0);
    __syncthreads();
    int cur = 0;
    const int NT = I_DIM / KC;             // 8
    for (int t = 0; t < NT; ++t) {
        const bool more = (t + 1 < NT);
        if (more) {
            A_STAGE(cur ^ 1, t + 1);
            B_LOAD(t + 1);
            __builtin_amdgcn_sched_barrier(0);
        }
#pragma unroll
        for (int kh = 0; kh < 2; ++kh) {
            bf16x8 a0 = *(const bf16x8*)&As[cur][ia0[kh]];
            bf16x8 a1 = *(const bf16x8*)&As[cur][ia1[kh]];
            bf16x8 b0 = *(const bf16x8*)&Bs[cur][ib0[kh]];
            bf16x8 b1 = *(const bf16x8*)&Bs[cur][ib1[kh]];
            acc[0][0] = __builtin_amdgcn_mfma_f32_16x16x32_bf16(a0, b0, acc[0][0], 0, 0, 0);
            acc[0][1] = __builtin_amdgcn_mfma_f32_16x16x32_bf16(a0, b1, acc[0][1], 0, 0, 0);
            acc[1][0] = __builtin_amdgcn_mfma_f32_16x16x32_bf16(a1, b0, acc[1][0], 0, 0, 0);
            acc[1][1] = __builtin_amdgcn_mfma_f32_16x16x32_bf16(a1, b1, acc[1][1], 0, 0, 0);
        }
        if (more) B_WRITE(cur ^ 1);
        __syncthreads();
        cur ^= 1;
    }
#undef A_STAGE
#undef B_LOAD
#undef B_WRITE

#pragma unroll
    for (int m = 0; m < 2; ++m)
#pragma unroll
        for (int n = 0; n < 2; ++n) {
            int col = h0 + wn * 32 + n * 16 + lr;
            int sbase2 = wm * 32 + m * 16 + lg * 4;
#pragma unroll
            for (int q = 0; q < 4; ++q) {
                int slot = sbase2 + q;
                int tok = toks[slot];
                if (tok >= 0)
                    atomicAdd(&out[(size_t)tok * H_DIM + col], acc[m][n][q] * wts[slot]);
            }
        }
}

extern "C" void kernel_launch(void* const* d_in, const int* in_sizes, int n_in,
                              void* d_out, int out_size, void* d_ws, size_t ws_size,
                              hipStream_t stream) {
    const float* hs   = (const float*)d_in[0];
    const float* gw   = (const float*)d_in[1];
    const float* bias = (const float*)d_in[2];
    const float* w13  = (const float*)d_in[3];
    const float* w2   = (const float*)d_in[4];
    float* out = (float*)d_out;

    char* ws = (char*)d_ws;
    int*   cnt      = (int*)(ws + 0);
    int*   tile_e   = (int*)(ws + 64);
    int*   tile_r0  = (int*)(ws + 384);
    int*   tok_list = (int*)(ws + 1024);
    float* w_list   = (float*)(ws + 132096);
    int*   A_tok    = (int*)(ws + 263168);
    float* A_w      = (float*)(ws + 283648);
    u16*   act      = (u16*)(ws + 304128);       // 5 MB
    u16*   hs_bf    = (u16*)(ws + 5547008);      // 8 MB -> ~13.6 MB total

    hipMemsetAsync(d_out, 0, (size_t)T_TOK * H_DIM * sizeof(float), stream);
    hipMemsetAsync(cnt, 0, 64, stream);

    router_kernel<<<T_TOK / 4, 256, 0, stream>>>(hs, gw, bias, cnt, tok_list, w_list, hs_bf);
    scatter_build<<<(E_EXP * T_TOK) / 256, 256, 0, stream>>>(cnt, tok_list, w_list, A_tok, A_w, tile_e, tile_r0);

    gemm1_act<<<MAX_TILES * 8, 256, 0, stream>>>(hs_bf, w13, A_tok, tile_e, tile_r0, act);
    gemm2_scatter<<<MAX_TILES * 32, 256, 0, stream>>>(act, w2, A_tok, A_w, tile_e, tile_r0, out);
}